// Round 1
// baseline (301.738 us; speedup 1.0000x reference)
//
#include <hip/hip_runtime.h>
#include <stdint.h>

// Problem constants (fixed by setup_inputs)
#define BATCH 64
#define NPTS  131072
#define MPTS  2048
#define CHUNK 1024
#define CPB   (NPTS / CHUNK)      // 128 chunks per batch
#define WORDS_PB (NPTS / 64)      // 2048 mask words per batch
#define WPC   (CHUNK / 64)        // 16 words per chunk

// ---------------- Threefry-2x32-20, exactly as jax/_src/prng.py ----------------
struct U2 { uint32_t a, b; };

__host__ __device__ constexpr U2 tf2x32(uint32_t k0, uint32_t k1, uint32_t x0, uint32_t x1) {
  uint32_t ks0 = k0, ks1 = k1, ks2 = k0 ^ k1 ^ 0x1BD11BDAu;
  x0 += ks0; x1 += ks1;
  const int rotA[4] = {13, 15, 26, 6};
  const int rotB[4] = {17, 29, 16, 24};
  for (int r = 0; r < 4; ++r) { x0 += x1; x1 = (x1 << rotA[r]) | (x1 >> (32 - rotA[r])); x1 ^= x0; }
  x0 += ks1; x1 += ks2 + 1u;
  for (int r = 0; r < 4; ++r) { x0 += x1; x1 = (x1 << rotB[r]) | (x1 >> (32 - rotB[r])); x1 ^= x0; }
  x0 += ks2; x1 += ks0 + 2u;
  for (int r = 0; r < 4; ++r) { x0 += x1; x1 = (x1 << rotA[r]) | (x1 >> (32 - rotA[r])); x1 ^= x0; }
  x0 += ks0; x1 += ks1 + 3u;
  for (int r = 0; r < 4; ++r) { x0 += x1; x1 = (x1 << rotB[r]) | (x1 >> (32 - rotB[r])); x1 ^= x0; }
  x0 += ks1; x1 += ks2 + 4u;
  for (int r = 0; r < 4; ++r) { x0 += x1; x1 = (x1 << rotA[r]) | (x1 >> (32 - rotA[r])); x1 ^= x0; }
  x0 += ks2; x1 += ks0 + 5u;
  return U2{x0, x1};
}

// ---------------- Pass 1: mask bits, per-chunk counts, masked xyz sums ----------------
__global__ __launch_bounds__(256) void pass1_kernel(
    const float4* __restrict__ pc, const float* __restrict__ lg,
    int* __restrict__ cnt, float* __restrict__ sums,
    int* __restrict__ blockCount, unsigned long long* __restrict__ maskWords) {
  int blk = blockIdx.x;
  int b = blk >> 7;          // / CPB
  int c = blk & (CPB - 1);
  int t = threadIdx.x;
  const float*  l0 = lg + (size_t)b * (2 * NPTS);
  const float*  l1 = l0 + NPTS;
  const float4* p4 = pc + (size_t)b * NPTS;
  int base = c * CHUNK;
  int   cntL = 0;
  float sx = 0.f, sy = 0.f, sz = 0.f;
#pragma unroll
  for (int k = 0; k < 4; ++k) {
    int i = base + k * 256 + t;
    bool m = l0[i] < l1[i];
    unsigned long long bal = __ballot((int)m);
    if ((t & 63) == 0)
      maskWords[(size_t)b * WORDS_PB + (i >> 6)] = bal;
    float4 p = p4[i];
    if (m) { cntL++; sx += p.x; sy += p.y; sz += p.z; }
  }
  // wave (64-lane) reduce, then cross-wave via LDS
  for (int o = 32; o; o >>= 1) {
    cntL += __shfl_down(cntL, o, 64);
    sx   += __shfl_down(sx,   o, 64);
    sy   += __shfl_down(sy,   o, 64);
    sz   += __shfl_down(sz,   o, 64);
  }
  __shared__ int   sc[4];
  __shared__ float ssx[4], ssy[4], ssz[4];
  int wave = t >> 6;
  if ((t & 63) == 0) { sc[wave] = cntL; ssx[wave] = sx; ssy[wave] = sy; ssz[wave] = sz; }
  __syncthreads();
  if (t == 0) {
    int   ct = sc[0] + sc[1] + sc[2] + sc[3];
    float fx = ssx[0] + ssx[1] + ssx[2] + ssx[3];
    float fy = ssy[0] + ssy[1] + ssy[2] + ssy[3];
    float fz = ssz[0] + ssz[1] + ssz[2] + ssz[3];
    blockCount[blk] = ct;
    atomicAdd(&cnt[b], ct);
    atomicAdd(&sums[b * 3 + 0], fx);
    atomicAdd(&sums[b * 3 + 1], fy);
    atomicAdd(&sums[b * 3 + 2], fz);
  }
}

// ---------------- Pass 2: per-batch chunk-offset scan + mean ----------------
__global__ __launch_bounds__(128) void pass2_kernel(
    const int* __restrict__ cnt, const float* __restrict__ sums,
    const int* __restrict__ blockCount, int* __restrict__ chunkOff,
    float* __restrict__ mean, float* __restrict__ out) {
  int b = blockIdx.x, t = threadIdx.x;
  __shared__ int s[CPB];
  int v = blockCount[b * CPB + t];
  s[t] = v;
  __syncthreads();
  for (int off = 1; off < CPB; off <<= 1) {
    int add = (t >= off) ? s[t - off] : 0;
    __syncthreads();
    s[t] += add;
    __syncthreads();
  }
  chunkOff[b * CPB + t] = s[t] - v;   // exclusive prefix
  if (t == 0) {
    int   ct = cnt[b];
    float d  = fmaxf((float)ct, 1.0f);
    float mx = sums[b * 3 + 0] / d;
    float my = sums[b * 3 + 1] / d;
    float mz = sums[b * 3 + 2] / d;
    mean[b * 3 + 0] = mx; mean[b * 3 + 1] = my; mean[b * 3 + 2] = mz;
    float* om = out + (size_t)BATCH * MPTS * 3 + (size_t)b * 3;
    om[0] = mx; om[1] = my; om[2] = mz;
  }
}

// ---------------- Pass 3: threefry randint + rank-select + gather ----------------
__global__ __launch_bounds__(256) void pass3_kernel(
    const float4* __restrict__ pc, const int* __restrict__ cnt,
    const float* __restrict__ mean, const int* __restrict__ chunkOff,
    const unsigned long long* __restrict__ maskWords,
    float* __restrict__ out) {
  int blk = blockIdx.x;
  int b = blk >> 3;                       // 8 blocks per batch (2048/256)
  int t = threadIdx.x;
  int j = (blk & 7) * 256 + t;
  int gid = b * MPTS + j;

  __shared__ int   sOff[CPB];
  __shared__ float sMean[3];
  __shared__ int   sCnt;
  if (t < CPB) sOff[t] = chunkOff[b * CPB + t];
  if (t < 3)   sMean[t] = mean[b * 3 + t];
  if (t == 0)  sCnt = cnt[b];
  __syncthreads();

  int cb = sCnt;
  float ox, oy, oz;
  if (cb == 0) {
    ox = oy = oz = (float)b;              // reference fills empty batches with batch id
  } else {
    // jax.random.randint(key(42),(B,M),0,max(cnt,1)) — partitionable threefry
    constexpr U2 K1 = tf2x32(0u, 42u, 0u, 0u);   // split(key)[0]
    constexpr U2 K2 = tf2x32(0u, 42u, 0u, 1u);   // split(key)[1]
    uint32_t span = (uint32_t)cb;
    U2 h = tf2x32(K1.a, K1.b, 0u, (uint32_t)gid);
    U2 l = tf2x32(K2.a, K2.b, 0u, (uint32_t)gid);
    uint32_t hb = h.a ^ h.b;              // higher_bits (32-bit fold)
    uint32_t lb = l.a ^ l.b;              // lower_bits
    uint32_t mul = 65536u % span;
    mul = (mul * mul) % span;             // uint32 wrap, exactly as lax
    uint32_t off = ((hb % span) * mul + (lb % span)) % span;
    int r = (j < cb && cb <= MPTS) ? j : (int)off;

    // rank-select: find chunk via binary search on exclusive offsets
    int lo = 0, hi = CPB - 1;
    while (lo < hi) {
      int mid = (lo + hi + 1) >> 1;
      if (sOff[mid] <= r) lo = mid; else hi = mid - 1;
    }
    int cIdx = lo;
    int rem = r - sOff[cIdx];
    const unsigned long long* mw = maskWords + (size_t)b * WORDS_PB + (size_t)cIdx * WPC;
    int wI = 0;
    unsigned long long word = mw[0];
    int pcw = __popcll(word);
    while (rem >= pcw) { rem -= pcw; ++wI; word = mw[wI]; pcw = __popcll(word); }
    for (int q = 0; q < rem; ++q) word &= word - 1ull;  // drop rem lowest set bits
    int bit = __builtin_ctzll(word);
    int idx = (cIdx * WPC + wI) * 64 + bit;

    float4 p = pc[(size_t)b * NPTS + idx];
    ox = p.x - sMean[0]; oy = p.y - sMean[1]; oz = p.z - sMean[2];
  }
  float* o = out + (size_t)gid * 3;
  o[0] = ox; o[1] = oy; o[2] = oz;
}

// ---------------- launch ----------------
extern "C" void kernel_launch(void* const* d_in, const int* in_sizes, int n_in,
                              void* d_out, int out_size, void* d_ws, size_t ws_size,
                              hipStream_t stream) {
  const float4* pc = (const float4*)d_in[0];   // (B, N, 4) float32
  const float*  lg = (const float*)d_in[1];    // (B, 2, N) float32
  float* out = (float*)d_out;                  // obj (B,M,3) then mean (B,3)

  char* w = (char*)d_ws;
  int*   cnt        = (int*)(w + 0);                 // 64 ints
  float* sums       = (float*)(w + 256);             // 64*3 floats
  float* mean       = (float*)(w + 1024);            // 64*3 floats
  int*   blockCount = (int*)(w + 2048);              // 64*128 ints
  int*   chunkOff   = (int*)(w + 2048 + 32768);      // 64*128 ints
  unsigned long long* maskWords =
      (unsigned long long*)(w + 2048 + 65536);       // 64*2048 u64 = 1 MiB

  hipMemsetAsync(d_ws, 0, 1024, stream);  // zero cnt + sums (ws is poisoned 0xAA)

  pass1_kernel<<<BATCH * CPB, 256, 0, stream>>>(pc, lg, cnt, sums, blockCount, maskWords);
  pass2_kernel<<<BATCH, CPB, 0, stream>>>(cnt, sums, blockCount, chunkOff, mean, out);
  pass3_kernel<<<(BATCH * MPTS) / 256, 256, 0, stream>>>(pc, cnt, mean, chunkOff, maskWords, out);
}

// Round 2
// 286.856 us; speedup vs baseline: 1.0519x; 1.0519x over previous
//
#include <hip/hip_runtime.h>
#include <stdint.h>

// Problem constants (fixed by setup_inputs)
#define BATCH 64
#define NPTS  131072
#define MPTS  2048
#define CHUNK 1024                 // points per pass1 block
#define CPB   (NPTS / CHUNK)       // 128 blocks per batch in pass1
#define WORDS_PB (NPTS / 64)       // 2048 mask words per batch

// ---------------- Threefry-2x32-20, exactly as jax/_src/prng.py ----------------
struct U2 { uint32_t a, b; };

__host__ __device__ constexpr U2 tf2x32(uint32_t k0, uint32_t k1, uint32_t x0, uint32_t x1) {
  uint32_t ks0 = k0, ks1 = k1, ks2 = k0 ^ k1 ^ 0x1BD11BDAu;
  x0 += ks0; x1 += ks1;
  const int rotA[4] = {13, 15, 26, 6};
  const int rotB[4] = {17, 29, 16, 24};
  for (int r = 0; r < 4; ++r) { x0 += x1; x1 = (x1 << rotA[r]) | (x1 >> (32 - rotA[r])); x1 ^= x0; }
  x0 += ks1; x1 += ks2 + 1u;
  for (int r = 0; r < 4; ++r) { x0 += x1; x1 = (x1 << rotB[r]) | (x1 >> (32 - rotB[r])); x1 ^= x0; }
  x0 += ks2; x1 += ks0 + 2u;
  for (int r = 0; r < 4; ++r) { x0 += x1; x1 = (x1 << rotA[r]) | (x1 >> (32 - rotA[r])); x1 ^= x0; }
  x0 += ks0; x1 += ks1 + 3u;
  for (int r = 0; r < 4; ++r) { x0 += x1; x1 = (x1 << rotB[r]) | (x1 >> (32 - rotB[r])); x1 ^= x0; }
  x0 += ks1; x1 += ks2 + 4u;
  for (int r = 0; r < 4; ++r) { x0 += x1; x1 = (x1 << rotA[r]) | (x1 >> (32 - rotA[r])); x1 ^= x0; }
  x0 += ks2; x1 += ks0 + 5u;
  return U2{x0, x1};
}

// ---------------- Pass 1: mask words + masked xyz sums ----------------
// Each thread handles 4 CONSECUTIVE points: 2 float4 logit loads + 4 float4
// point loads, all independent and issued straight-line (ILP: ~24 dwords in
// flight per thread — the R0 version had VGPR_Count=12 and serialized).
__global__ __launch_bounds__(256) void pass1_kernel(
    const float4* __restrict__ pc, const float4* __restrict__ lg4,
    float* __restrict__ sums, unsigned long long* __restrict__ maskWords) {
  int blk = blockIdx.x;
  int b = blk >> 7;          // / CPB
  int c = blk & (CPB - 1);
  int t = threadIdx.x;

  // logits (B,2,N) as float4: batch base = b*2*N/4, l1 at +N/4
  size_t lbase = (size_t)b * (2 * NPTS / 4) + (size_t)c * (CHUNK / 4) + t;
  float4 a  = lg4[lbase];                  // l0 for points 4t..4t+3
  float4 bb = lg4[lbase + NPTS / 4];       // l1
  size_t pbase = (size_t)b * NPTS + (size_t)c * CHUNK + 4 * t;
  float4 p0 = pc[pbase + 0];
  float4 p1 = pc[pbase + 1];
  float4 p2 = pc[pbase + 2];
  float4 p3 = pc[pbase + 3];

  bool m0 = a.x < bb.x, m1 = a.y < bb.y, m2 = a.z < bb.z, m3 = a.w < bb.w;
  unsigned nib = (unsigned)m0 | ((unsigned)m1 << 1) | ((unsigned)m2 << 2) | ((unsigned)m3 << 3);

  // pack nibbles -> 16 u64 mask words per block via LDS
  __shared__ unsigned char sNib[256];
  sNib[t] = (unsigned char)nib;
  __syncthreads();
  if (t < 16) {
    const uint32_t* sN32 = (const uint32_t*)sNib;
    unsigned long long w = 0ull;
#pragma unroll
    for (int q = 0; q < 4; ++q) {
      uint32_t u = sN32[t * 4 + q];        // 4 threads' nibbles (bytes)
      w |= (unsigned long long)( u        & 0x0Fu) << (q * 16 + 0);
      w |= (unsigned long long)((u >> 8)  & 0x0Fu) << (q * 16 + 4);
      w |= (unsigned long long)((u >> 16) & 0x0Fu) << (q * 16 + 8);
      w |= (unsigned long long)((u >> 24) & 0x0Fu) << (q * 16 + 12);
    }
    maskWords[(size_t)b * WORDS_PB + c * 16 + t] = w;
  }

  float sx = (m0 ? p0.x : 0.f) + (m1 ? p1.x : 0.f) + (m2 ? p2.x : 0.f) + (m3 ? p3.x : 0.f);
  float sy = (m0 ? p0.y : 0.f) + (m1 ? p1.y : 0.f) + (m2 ? p2.y : 0.f) + (m3 ? p3.y : 0.f);
  float sz = (m0 ? p0.z : 0.f) + (m1 ? p1.z : 0.f) + (m2 ? p2.z : 0.f) + (m3 ? p3.z : 0.f);

  // wave (64-lane) reduce, then cross-wave via LDS
  for (int o = 32; o; o >>= 1) {
    sx += __shfl_down(sx, o, 64);
    sy += __shfl_down(sy, o, 64);
    sz += __shfl_down(sz, o, 64);
  }
  __shared__ float ssx[4], ssy[4], ssz[4];
  int wave = t >> 6;
  if ((t & 63) == 0) { ssx[wave] = sx; ssy[wave] = sy; ssz[wave] = sz; }
  __syncthreads();
  if (t == 0) {
    atomicAdd(&sums[b * 3 + 0], ssx[0] + ssx[1] + ssx[2] + ssx[3]);
    atomicAdd(&sums[b * 3 + 1], ssy[0] + ssy[1] + ssy[2] + ssy[3]);
    atomicAdd(&sums[b * 3 + 2], ssz[0] + ssz[1] + ssz[2] + ssz[3]);
  }
}

// ---------------- Pass 2: word-level exclusive prefix + count + mean ----------------
// One block per batch, 256 threads, 8 words/thread (blocked).
__global__ __launch_bounds__(256) void pass2_kernel(
    const unsigned long long* __restrict__ maskWords, const float* __restrict__ sums,
    uint32_t* __restrict__ wordOff, int* __restrict__ cnt,
    float* __restrict__ mean, float* __restrict__ out) {
  int b = blockIdx.x, t = threadIdx.x;
  const unsigned long long* mw = maskWords + (size_t)b * WORDS_PB;
  int base = t * 8;
  int p[8];
  int local = 0;
#pragma unroll
  for (int k = 0; k < 8; ++k) { p[k] = __popcll(mw[base + k]); local += p[k]; }

  __shared__ int s[256];
  s[t] = local;
  __syncthreads();
  for (int off = 1; off < 256; off <<= 1) {
    int add = (t >= off) ? s[t - off] : 0;
    __syncthreads();
    s[t] += add;
    __syncthreads();
  }
  int run = s[t] - local;                  // exclusive prefix of this thread's group
  uint32_t* wo = wordOff + (size_t)b * WORDS_PB;
#pragma unroll
  for (int k = 0; k < 8; ++k) { wo[base + k] = (uint32_t)run; run += p[k]; }

  if (t == 255) {
    int ct = run;                          // total masked count for batch b
    cnt[b] = ct;
    float d  = fmaxf((float)ct, 1.0f);
    float mx = sums[b * 3 + 0] / d;
    float my = sums[b * 3 + 1] / d;
    float mz = sums[b * 3 + 2] / d;
    mean[b * 3 + 0] = mx; mean[b * 3 + 1] = my; mean[b * 3 + 2] = mz;
    float* om = out + (size_t)BATCH * MPTS * 3 + (size_t)b * 3;
    om[0] = mx; om[1] = my; om[2] = mz;
  }
}

// ---------------- Pass 3: threefry randint + rank-select + gather ----------------
__global__ __launch_bounds__(256) void pass3_kernel(
    const float4* __restrict__ pc, const int* __restrict__ cnt,
    const float* __restrict__ mean, const uint32_t* __restrict__ wordOff,
    const unsigned long long* __restrict__ maskWords,
    float* __restrict__ out) {
  int blk = blockIdx.x;
  int b = blk >> 3;                        // 8 blocks per batch (2048/256)
  int t = threadIdx.x;
  int j = (blk & 7) * 256 + t;
  int gid = b * MPTS + j;

  __shared__ uint32_t sOff[WORDS_PB];      // 8 KiB: full word-level prefix for batch b
  __shared__ float sMean[3];
  __shared__ int sCnt;
  const uint32_t* wo = wordOff + (size_t)b * WORDS_PB;
#pragma unroll
  for (int k = 0; k < 8; ++k) sOff[t + k * 256] = wo[t + k * 256];
  if (t < 3)  sMean[t] = mean[b * 3 + t];
  if (t == 0) sCnt = cnt[b];
  __syncthreads();

  int cb = sCnt;
  float ox, oy, oz;
  if (cb == 0) {
    ox = oy = oz = (float)b;               // reference fills empty batches with batch id
  } else {
    // jax.random.randint(key(42),(B,M),0,max(cnt,1)) — partitionable threefry
    constexpr U2 K1 = tf2x32(0u, 42u, 0u, 0u);   // split(key)[0]
    constexpr U2 K2 = tf2x32(0u, 42u, 0u, 1u);   // split(key)[1]
    uint32_t span = (uint32_t)cb;
    U2 h = tf2x32(K1.a, K1.b, 0u, (uint32_t)gid);
    U2 l = tf2x32(K2.a, K2.b, 0u, (uint32_t)gid);
    uint32_t hb = h.a ^ h.b;               // higher_bits (32-bit fold)
    uint32_t lb = l.a ^ l.b;               // lower_bits
    uint32_t mul = 65536u % span;
    mul = (mul * mul) % span;              // uint32 wrap, exactly as lax
    uint32_t off = ((hb % span) * mul + (lb % span)) % span;
    int r = (j < cb && cb <= MPTS) ? j : (int)off;

    // binary search: largest w with sOff[w] <= r (sOff[0]==0)
    int lo = 0;
#pragma unroll
    for (int step = 1024; step; step >>= 1) {
      int nxt = lo + step;
      if (nxt < WORDS_PB && sOff[nxt] <= (uint32_t)r) lo = nxt;
    }
    int rem = r - (int)sOff[lo];
    unsigned long long w = maskWords[(size_t)b * WORDS_PB + lo];

    // branchless 64-bit rank-select of the rem-th set bit
    uint32_t cur = (uint32_t)w;
    int bitbase = 0;
    int c = __popc(cur);
    if (rem >= c) { rem -= c; cur = (uint32_t)(w >> 32); bitbase = 32; }
    c = __popc(cur & 0xFFFFu); if (rem >= c) { rem -= c; cur >>= 16; bitbase += 16; }
    c = __popc(cur & 0xFFu);   if (rem >= c) { rem -= c; cur >>= 8;  bitbase += 8;  }
    c = __popc(cur & 0xFu);    if (rem >= c) { rem -= c; cur >>= 4;  bitbase += 4;  }
    c = __popc(cur & 0x3u);    if (rem >= c) { rem -= c; cur >>= 2;  bitbase += 2;  }
    c = (int)(cur & 1u);       if (rem >= c) {           cur >>= 1;  bitbase += 1;  }
    int idx = lo * 64 + bitbase;

    float4 p = pc[(size_t)b * NPTS + idx];
    ox = p.x - sMean[0]; oy = p.y - sMean[1]; oz = p.z - sMean[2];
  }
  float* o = out + (size_t)gid * 3;
  o[0] = ox; o[1] = oy; o[2] = oz;
}

// ---------------- launch ----------------
extern "C" void kernel_launch(void* const* d_in, const int* in_sizes, int n_in,
                              void* d_out, int out_size, void* d_ws, size_t ws_size,
                              hipStream_t stream) {
  const float4* pc  = (const float4*)d_in[0];   // (B, N, 4) float32
  const float4* lg4 = (const float4*)d_in[1];   // (B, 2, N) float32 as float4
  float* out = (float*)d_out;                   // obj (B,M,3) then mean (B,3)

  char* w = (char*)d_ws;
  int*      cnt     = (int*)(w + 0);                       // 64 ints
  float*    sums    = (float*)(w + 256);                   // 64*3 floats
  float*    mean    = (float*)(w + 1024);                  // 64*3 floats
  uint32_t* wordOff = (uint32_t*)(w + 4096);               // 64*2048 u32 = 512 KiB
  unsigned long long* maskWords =
      (unsigned long long*)(w + 4096 + 524288);            // 64*2048 u64 = 1 MiB

  hipMemsetAsync(w + 256, 0, 768, stream);  // zero sums (ws is poisoned 0xAA)

  pass1_kernel<<<BATCH * CPB, 256, 0, stream>>>(pc, lg4, sums, maskWords);
  pass2_kernel<<<BATCH, 256, 0, stream>>>(maskWords, sums, wordOff, cnt, mean, out);
  pass3_kernel<<<(BATCH * MPTS) / 256, 256, 0, stream>>>(pc, cnt, mean, wordOff, maskWords, out);
}

// Round 3
// 248.696 us; speedup vs baseline: 1.2133x; 1.1534x over previous
//
#include <hip/hip_runtime.h>
#include <stdint.h>

// Problem constants (fixed by setup_inputs)
#define BATCH 64
#define NPTS  131072
#define MPTS  2048
#define WORDS_PB (NPTS / 64)       // 2048 mask words per batch
#define P1_PPB 4096                // points per pass1 block (divides NPTS)
#define P1_BLOCKS (BATCH * NPTS / P1_PPB)   // 2048

// ---------------- Threefry-2x32-20, exactly as jax/_src/prng.py ----------------
struct U2 { uint32_t a, b; };

__host__ __device__ constexpr U2 tf2x32(uint32_t k0, uint32_t k1, uint32_t x0, uint32_t x1) {
  uint32_t ks0 = k0, ks1 = k1, ks2 = k0 ^ k1 ^ 0x1BD11BDAu;
  x0 += ks0; x1 += ks1;
  const int rotA[4] = {13, 15, 26, 6};
  const int rotB[4] = {17, 29, 16, 24};
  for (int r = 0; r < 4; ++r) { x0 += x1; x1 = (x1 << rotA[r]) | (x1 >> (32 - rotA[r])); x1 ^= x0; }
  x0 += ks1; x1 += ks2 + 1u;
  for (int r = 0; r < 4; ++r) { x0 += x1; x1 = (x1 << rotB[r]) | (x1 >> (32 - rotB[r])); x1 ^= x0; }
  x0 += ks2; x1 += ks0 + 2u;
  for (int r = 0; r < 4; ++r) { x0 += x1; x1 = (x1 << rotA[r]) | (x1 >> (32 - rotA[r])); x1 ^= x0; }
  x0 += ks0; x1 += ks1 + 3u;
  for (int r = 0; r < 4; ++r) { x0 += x1; x1 = (x1 << rotB[r]) | (x1 >> (32 - rotB[r])); x1 ^= x0; }
  x0 += ks1; x1 += ks2 + 4u;
  for (int r = 0; r < 4; ++r) { x0 += x1; x1 = (x1 << rotA[r]) | (x1 >> (32 - rotA[r])); x1 ^= x0; }
  x0 += ks2; x1 += ks0 + 5u;
  return U2{x0, x1};
}

// ---------------- Pass 1: streaming mask + masked xyz sums ----------------
// 16 points per thread, thread<->point 1:1 (all loads coalesced), unroll 8.
// Wave = exactly one 64-bit mask word per iteration via __ballot.
// Block = 4096 consecutive points = single batch (4096 | 131072).
__global__ __launch_bounds__(256) void pass1_kernel(
    const float4* __restrict__ pc, const float* __restrict__ lg,
    float* __restrict__ sums, unsigned long long* __restrict__ maskWords) {
  int blk = blockIdx.x;
  int t = threadIdx.x;
  size_t pbase = (size_t)blk * P1_PPB;       // global point index base
  int b = (int)(pbase >> 17);                // / NPTS
  // l0 for global point p lives at lg[b*N + p]; l1 at lg[(b+1)*N + p]
  const float* l0g = lg + (size_t)b * NPTS;
  const float* l1g = lg + (size_t)(b + 1) * NPTS;

  float sx = 0.f, sy = 0.f, sz = 0.f;
#pragma unroll 2
  for (int half = 0; half < 2; ++half) {
#pragma unroll
    for (int k = 0; k < 8; ++k) {
      size_t p = pbase + (size_t)(half * 8 + k) * 256 + t;
      float a0 = l0g[p];
      float a1 = l1g[p];
      float4 q = pc[p];
      bool m = a0 < a1;
      unsigned long long bal = __ballot(m);
      if ((t & 63) == 0) maskWords[p >> 6] = bal;   // p%64==0 for lane 0
      if (m) { sx += q.x; sy += q.y; sz += q.z; }
    }
  }

  // wave (64-lane) reduce, then cross-wave via LDS
  for (int o = 32; o; o >>= 1) {
    sx += __shfl_down(sx, o, 64);
    sy += __shfl_down(sy, o, 64);
    sz += __shfl_down(sz, o, 64);
  }
  __shared__ float ssx[4], ssy[4], ssz[4];
  int wave = t >> 6;
  if ((t & 63) == 0) { ssx[wave] = sx; ssy[wave] = sy; ssz[wave] = sz; }
  __syncthreads();
  if (t == 0) {
    atomicAdd(&sums[b * 3 + 0], ssx[0] + ssx[1] + ssx[2] + ssx[3]);
    atomicAdd(&sums[b * 3 + 1], ssy[0] + ssy[1] + ssy[2] + ssy[3]);
    atomicAdd(&sums[b * 3 + 2], ssz[0] + ssz[1] + ssz[2] + ssz[3]);
  }
}

// ---------------- Pass 2: word-level exclusive prefix + count + mean ----------------
// One block per batch, 256 threads, 8 words/thread; shuffle-based scan.
__global__ __launch_bounds__(256) void pass2_kernel(
    const unsigned long long* __restrict__ maskWords, const float* __restrict__ sums,
    uint32_t* __restrict__ wordOff, int* __restrict__ cnt,
    float* __restrict__ mean, float* __restrict__ out) {
  int b = blockIdx.x, t = threadIdx.x;
  int lane = t & 63, wv = t >> 6;
  const unsigned long long* mw = maskWords + (size_t)b * WORDS_PB;
  int base = t * 8;
  int p[8];
  int local = 0;
#pragma unroll
  for (int k = 0; k < 8; ++k) { p[k] = __popcll(mw[base + k]); local += p[k]; }

  // wave-level inclusive scan of `local`
  int x = local;
#pragma unroll
  for (int o = 1; o < 64; o <<= 1) {
    int y = __shfl_up(x, o, 64);
    if (lane >= o) x += y;
  }
  __shared__ int wsum[4];
  if (lane == 63) wsum[wv] = x;
  __syncthreads();
  int add = 0;
#pragma unroll
  for (int u = 0; u < 4; ++u) add += (u < wv) ? wsum[u] : 0;
  int run = add + x - local;               // exclusive prefix for this thread's 8 words
  uint32_t* wo = wordOff + (size_t)b * WORDS_PB;
#pragma unroll
  for (int k = 0; k < 8; ++k) { wo[base + k] = (uint32_t)run; run += p[k]; }

  if (t == 0) {
    int ct = wsum[0] + wsum[1] + wsum[2] + wsum[3];
    cnt[b] = ct;
    float d  = fmaxf((float)ct, 1.0f);
    float mx = sums[b * 3 + 0] / d;
    float my = sums[b * 3 + 1] / d;
    float mz = sums[b * 3 + 2] / d;
    mean[b * 3 + 0] = mx; mean[b * 3 + 1] = my; mean[b * 3 + 2] = mz;
    float* om = out + (size_t)BATCH * MPTS * 3 + (size_t)b * 3;
    om[0] = mx; om[1] = my; om[2] = mz;
  }
}

// ---------------- Pass 3: threefry randint + rank-select + gather ----------------
__global__ __launch_bounds__(256) void pass3_kernel(
    const float4* __restrict__ pc, const int* __restrict__ cnt,
    const float* __restrict__ mean, const uint32_t* __restrict__ wordOff,
    const unsigned long long* __restrict__ maskWords,
    float* __restrict__ out) {
  int blk = blockIdx.x;
  int b = blk >> 3;                        // 8 blocks per batch (2048/256)
  int t = threadIdx.x;
  int j = (blk & 7) * 256 + t;
  int gid = b * MPTS + j;

  __shared__ uint32_t sOff[WORDS_PB];      // 8 KiB: full word-level prefix for batch b
  __shared__ float sMean[3];
  __shared__ int sCnt;
  const uint32_t* wo = wordOff + (size_t)b * WORDS_PB;
#pragma unroll
  for (int k = 0; k < 8; ++k) sOff[t + k * 256] = wo[t + k * 256];
  if (t < 3)  sMean[t] = mean[b * 3 + t];
  if (t == 0) sCnt = cnt[b];
  __syncthreads();

  int cb = sCnt;
  float ox, oy, oz;
  if (cb == 0) {
    ox = oy = oz = (float)b;               // reference fills empty batches with batch id
  } else {
    // jax.random.randint(key(42),(B,M),0,max(cnt,1)) — partitionable threefry
    constexpr U2 K1 = tf2x32(0u, 42u, 0u, 0u);   // split(key)[0]
    constexpr U2 K2 = tf2x32(0u, 42u, 0u, 1u);   // split(key)[1]
    uint32_t span = (uint32_t)cb;
    U2 h = tf2x32(K1.a, K1.b, 0u, (uint32_t)gid);
    U2 l = tf2x32(K2.a, K2.b, 0u, (uint32_t)gid);
    uint32_t hb = h.a ^ h.b;               // higher_bits (32-bit fold)
    uint32_t lb = l.a ^ l.b;               // lower_bits
    uint32_t mul = 65536u % span;
    mul = (mul * mul) % span;              // uint32 wrap, exactly as lax
    uint32_t off = ((hb % span) * mul + (lb % span)) % span;
    int r = (j < cb && cb <= MPTS) ? j : (int)off;

    // binary search: largest w with sOff[w] <= r (sOff[0]==0)
    int lo = 0;
#pragma unroll
    for (int step = 1024; step; step >>= 1) {
      int nxt = lo + step;
      if (nxt < WORDS_PB && sOff[nxt] <= (uint32_t)r) lo = nxt;
    }
    int rem = r - (int)sOff[lo];
    unsigned long long w = maskWords[(size_t)b * WORDS_PB + lo];

    // branchless 64-bit rank-select of the rem-th set bit
    uint32_t cur = (uint32_t)w;
    int bitbase = 0;
    int c = __popc(cur);
    if (rem >= c) { rem -= c; cur = (uint32_t)(w >> 32); bitbase = 32; }
    c = __popc(cur & 0xFFFFu); if (rem >= c) { rem -= c; cur >>= 16; bitbase += 16; }
    c = __popc(cur & 0xFFu);   if (rem >= c) { rem -= c; cur >>= 8;  bitbase += 8;  }
    c = __popc(cur & 0xFu);    if (rem >= c) { rem -= c; cur >>= 4;  bitbase += 4;  }
    c = __popc(cur & 0x3u);    if (rem >= c) { rem -= c; cur >>= 2;  bitbase += 2;  }
    c = (int)(cur & 1u);       if (rem >= c) {           cur >>= 1;  bitbase += 1;  }
    int idx = lo * 64 + bitbase;

    float4 p = pc[(size_t)b * NPTS + idx];
    ox = p.x - sMean[0]; oy = p.y - sMean[1]; oz = p.z - sMean[2];
  }
  float* o = out + (size_t)gid * 3;
  o[0] = ox; o[1] = oy; o[2] = oz;
}

// ---------------- launch ----------------
extern "C" void kernel_launch(void* const* d_in, const int* in_sizes, int n_in,
                              void* d_out, int out_size, void* d_ws, size_t ws_size,
                              hipStream_t stream) {
  const float4* pc = (const float4*)d_in[0];   // (B, N, 4) float32
  const float*  lg = (const float*)d_in[1];    // (B, 2, N) float32
  float* out = (float*)d_out;                  // obj (B,M,3) then mean (B,3)

  char* w = (char*)d_ws;
  float*    sums    = (float*)(w + 0);                     // 64*3 floats (768 B)
  int*      cnt     = (int*)(w + 1024);                    // 64 ints
  float*    mean    = (float*)(w + 2048);                  // 64*3 floats
  uint32_t* wordOff = (uint32_t*)(w + 4096);               // 64*2048 u32 = 512 KiB
  unsigned long long* maskWords =
      (unsigned long long*)(w + 4096 + 524288);            // 64*2048 u64 = 1 MiB

  hipMemsetAsync(sums, 0, 768, stream);  // ws is poisoned 0xAA; sums accumulates

  pass1_kernel<<<P1_BLOCKS, 256, 0, stream>>>(pc, lg, sums, maskWords);
  pass2_kernel<<<BATCH, 256, 0, stream>>>(maskWords, sums, wordOff, cnt, mean, out);
  pass3_kernel<<<(BATCH * MPTS) / 256, 256, 0, stream>>>(pc, cnt, mean, wordOff, maskWords, out);
}